// Round 7
// baseline (949.348 us; speedup 1.0000x reference)
//
#include <hip/hip_runtime.h>
#include <math.h>

// EM routing, fully fused: one block per (b, l) output position, 512 threads.
// A=32, B=32, PSIZE=16 (4x4), K=3, STRIDE=2, PAD=1, ITERS=3.
// Input 14x14 -> output 7x7 (l = 49). kkA = 9*32 = 288.
//
// Mapping: c = tid&31 (capsule, lane bits 0-4), g = tid>>5 (k-group 0..15,
// thread owns k = 16j+g, j=0..17). r~ = r*au lives ENTIRELY in registers
// (r_reg[18], fully unrolled). Softmax over c is intra-wave shfl butterflies.
// Moments reduce: shfl_xor(32) for g-pairs, then 8-wave LDS partials (s12).
//
// LDS (64000 B): pu 23040 | red_a/red_b 2x1024 | s12 34816 | mu/is2 2x2048
// Barriers: 3 per iteration. WAR audit: red_a W(<B1)/R(B1..B2), next W after
// B2,B3; red_b W(B2..B3)/R(>B3), next W after B1',B2'; s12 W(B1..B2)/R(B2..B3);
// mu_t W(B2..B3)/R(>B3). All separated by >=2 barriers.

#define KKA_    288
#define L_      49
#define OH_     7
#define EPSF    1e-12f
#define PUST    20              // pu row stride (80 B, 16B-aligned for b128)
#define S12ST   34              // s12 row stride (136 B, 8B-aligned, 2-way bank)
#define LOG_LN2PI 0.60861006f   // log(log(2*pi))

__global__ __launch_bounds__(512, 2) void em_routing_kernel(
    const float* __restrict__ a_in,   // (8, 32, 14, 14)
    const float* __restrict__ pose,   // (8, 512, 14, 14)
    const float* __restrict__ W,      // (288, 32, 4, 4)
    const float* __restrict__ beta_u, // (32)
    const float* __restrict__ beta_a, // (32)
    float* __restrict__ out)          // a_o (8,32,7,7) then pose_out (8,512,7,7)
{
    __shared__ float pu_lds[KKA_ * PUST];    // 23040 B, au[k] at pad slot 16
    __shared__ float red_a[8 * 32];          // 1024 B  rsum partials
    __shared__ float red_b[8 * 32];          // 1024 B  Ls partials
    __shared__ float s12[8 * 32 * S12ST];    // 34816 B per-wave S1/S2 partials
    __shared__ float mu_t[16 * 32];          // 2048 B  mu[p][c]
    __shared__ float is2_t[16 * 32];         // 2048 B  0.5/sigma^2 [p][c]

    const int tid = threadIdx.x;
    const int bl = blockIdx.x;
    const int b  = bl / L_;
    const int l  = bl % L_;
    const int oy = l / OH_, ox = l % OH_;

    // ---- stage pu (pose unfold patch), stride-20 rows ----
    for (int q = tid; q < KKA_ * 16; q += 512) {
        const int k = q >> 4, p = q & 15;
        const int a = k & 31, kki = k >> 5;
        const int ki = kki / 3, kj = kki % 3;
        const int iy = oy * 2 + ki - 1, ix = ox * 2 + kj - 1;
        float v = 0.f;
        if ((unsigned)iy < 14u && (unsigned)ix < 14u)
            v = pose[(b * 512 + a * 16 + p) * 196 + iy * 14 + ix];
        pu_lds[k * PUST + p] = v;
    }
    // ---- stage au into pu pad slot 16 (512 threads >= 288: single shot) ----
    if (tid < KKA_) {
        const int k = tid;
        const int a = k & 31, kki = k >> 5;
        const int ki = kki / 3, kj = kki % 3;
        const int iy = oy * 2 + ki - 1, ix = ox * 2 + kj - 1;
        float v = 0.f;
        if ((unsigned)iy < 14u && (unsigned)ix < 14u)
            v = a_in[(b * 32 + a) * 196 + iy * 14 + ix];
        pu_lds[k * PUST + 16] = v;
    }
    __syncthreads();

    const int c    = tid & 31;      // capsule (lane bits 0-4)
    const int g    = tid >> 5;      // k-group 0..15 (bit0 = lane bit5)
    const int lane = tid & 63;
    const int w    = tid >> 6;      // wave 0..7

    const float bu_c = beta_u[c];
    const float ba_c = beta_a[c];

    // ---- r~ = r*au in registers; init r=1 -> r~ = au ----
    float r_reg[18];
    #pragma unroll
    for (int j = 0; j < 18; ++j)
        r_reg[j] = pu_lds[(16 * j + g) * PUST + 16];

    for (int it = 0; it < 3; ++it) {
        const float lam = (it == 0) ? 0.0005f : ((it == 1) ? 0.000975f : 0.00142625f);

        // ---- step 1: rsum[c] = sum_k r~ ----
        float pa = 0.f, pb = 0.f;
        #pragma unroll
        for (int j = 0; j < 18; j += 2) { pa += r_reg[j]; pb += r_reg[j + 1]; }
        float part = pa + pb;
        part += __shfl_xor(part, 32);           // combine g-pair within wave
        if (lane < 32) red_a[w * 32 + c] = part;
        __syncthreads();                        // B1
        float rsum = 0.f;
        #pragma unroll
        for (int ww = 0; ww < 8; ++ww) rsum += red_a[ww * 32 + c];
        const float invr = 1.0f / (rsum + EPSF);

        // ---- P23: moments over this thread's 18 k's, 16 p's each ----
        float S1[16], S2[16];
        #pragma unroll
        for (int t = 0; t < 16; ++t) { S1[t] = 0.f; S2[t] = 0.f; }
        const float* pW = W + g * 512 + c * 16;
        #pragma unroll
        for (int j = 0; j < 18; ++j) {
            const int k = 16 * j + g;
            const float cf = r_reg[j] * invr;
            const float4 w0 = *(const float4*)(pW);
            const float4 w1 = *(const float4*)(pW + 4);
            const float4 w2 = *(const float4*)(pW + 8);
            const float4 w3 = *(const float4*)(pW + 12);
            pW += 8192;
            const float* pk = &pu_lds[k * PUST];
            #pragma unroll
            for (int i = 0; i < 4; ++i) {
                const float4 pu4 = *(const float4*)(pk + (i << 2));
                float v, cv;
                v = pu4.x * w0.x + pu4.y * w1.x + pu4.z * w2.x + pu4.w * w3.x;
                cv = cf * v; S1[i * 4 + 0] += cv; S2[i * 4 + 0] += cv * v;
                v = pu4.x * w0.y + pu4.y * w1.y + pu4.z * w2.y + pu4.w * w3.y;
                cv = cf * v; S1[i * 4 + 1] += cv; S2[i * 4 + 1] += cv * v;
                v = pu4.x * w0.z + pu4.y * w1.z + pu4.z * w2.z + pu4.w * w3.z;
                cv = cf * v; S1[i * 4 + 2] += cv; S2[i * 4 + 2] += cv * v;
                v = pu4.x * w0.w + pu4.y * w1.w + pu4.z * w2.w + pu4.w * w3.w;
                cv = cf * v; S1[i * 4 + 3] += cv; S2[i * 4 + 3] += cv * v;
            }
        }
        // combine g-pair within wave, then publish per-wave partials
        #pragma unroll
        for (int t = 0; t < 16; ++t) {
            S1[t] += __shfl_xor(S1[t], 32);
            S2[t] += __shfl_xor(S2[t], 32);
        }
        if (lane < 32) {
            float* dst = &s12[(w * 32 + c) * S12ST];
            #pragma unroll
            for (int t = 0; t < 16; t += 2) {
                *(float2*)(dst + t)      = make_float2(S1[t], S1[t + 1]);
                *(float2*)(dst + 16 + t) = make_float2(S2[t], S2[t + 1]);
            }
        }
        __syncthreads();                        // B2

        // ---- stats: thread (c, p=g) handles one p ----
        const int p = g;
        float m = 0.f, e2 = 0.f;
        #pragma unroll
        for (int ww = 0; ww < 8; ++ww) {
            const float* src = &s12[(ww * 32 + c) * S12ST];
            m  += src[p];
            e2 += src[16 + p];
        }
        const float ss = fmaxf(e2 - m * m, 0.f) + EPSF;
        float lps = __logf(ss);
        lps += __shfl_xor(lps, 32);             // combine p-pair within wave
        if (lane < 32) red_b[w * 32 + c] = lps;
        if (it == 2) {
            out[12544 + (b * 512 + (c << 4) + p) * 49 + l] = m;
        } else {
            mu_t[p * 32 + c]  = m;
            is2_t[p * 32 + c] = 0.5f / ss;
        }
        __syncthreads();                        // B3
        float Ls = 0.f;
        #pragma unroll
        for (int ww = 0; ww < 8; ++ww) Ls += red_b[ww * 32 + c];
        const float cost = rsum * (16.f * bu_c + 0.5f * Ls);
        const float aout = 1.f / (1.f + __expf(-(lam * (ba_c - cost))));

        if (it == 2) {
            if (g == 0) out[(b * 32 + c) * 49 + l] = aout;
        } else {
            const float m1c = -0.5f * (Ls + 16.f * LOG_LN2PI) + __logf(aout);
            // ---- P4 + in-register softmax over c (intra-wave) ----
            float mu_r[16], is2_r[16];
            #pragma unroll
            for (int pp = 0; pp < 16; ++pp) {
                mu_r[pp]  = mu_t[pp * 32 + c];
                is2_r[pp] = is2_t[pp * 32 + c];
            }
            const float* pW4 = W + g * 512 + c * 16;
            #pragma unroll
            for (int j = 0; j < 18; ++j) {
                const int k = 16 * j + g;
                const float4 wr0 = *(const float4*)(pW4);
                const float4 wr1 = *(const float4*)(pW4 + 4);
                const float4 wr2 = *(const float4*)(pW4 + 8);
                const float4 wr3 = *(const float4*)(pW4 + 12);
                pW4 += 8192;
                float q = 0.f;
                #pragma unroll
                for (int i = 0; i < 4; ++i) {
                    const float4 pui = *(const float4*)&pu_lds[k * PUST + (i << 2)];
                    float vv, d;
                    vv = pui.x * wr0.x + pui.y * wr1.x + pui.z * wr2.x + pui.w * wr3.x;
                    d = vv - mu_r[i * 4 + 0]; q += d * d * is2_r[i * 4 + 0];
                    vv = pui.x * wr0.y + pui.y * wr1.y + pui.z * wr2.y + pui.w * wr3.y;
                    d = vv - mu_r[i * 4 + 1]; q += d * d * is2_r[i * 4 + 1];
                    vv = pui.x * wr0.z + pui.y * wr1.z + pui.z * wr2.z + pui.w * wr3.z;
                    d = vv - mu_r[i * 4 + 2]; q += d * d * is2_r[i * 4 + 2];
                    vv = pui.x * wr0.w + pui.y * wr1.w + pui.z * wr2.w + pui.w * wr3.w;
                    d = vv - mu_r[i * 4 + 3]; q += d * d * is2_r[i * 4 + 3];
                }
                const float la = m1c - q;
                // softmax over the 32 c-lanes (intra-wave butterflies)
                float mx = la;
                mx = fmaxf(mx, __shfl_xor(mx, 1));
                mx = fmaxf(mx, __shfl_xor(mx, 2));
                mx = fmaxf(mx, __shfl_xor(mx, 4));
                mx = fmaxf(mx, __shfl_xor(mx, 8));
                mx = fmaxf(mx, __shfl_xor(mx, 16));
                const float e = __expf(la - mx);
                float se = e;
                se += __shfl_xor(se, 1);
                se += __shfl_xor(se, 2);
                se += __shfl_xor(se, 4);
                se += __shfl_xor(se, 8);
                se += __shfl_xor(se, 16);
                r_reg[j] = e * pu_lds[k * PUST + 16] / se;   // fold au back in
            }
            // no barrier needed: next phase touches only registers + red_a
            // (red_a's last read was before B2; >=2 barriers separate)
        }
    }
}

extern "C" void kernel_launch(void* const* d_in, const int* in_sizes, int n_in,
                              void* d_out, int out_size, void* d_ws, size_t ws_size,
                              hipStream_t stream) {
    const float* a_in   = (const float*)d_in[0];
    const float* pose   = (const float*)d_in[1];
    const float* W      = (const float*)d_in[2];
    const float* beta_u = (const float*)d_in[3];
    const float* beta_a = (const float*)d_in[4];
    float* out = (float*)d_out;
    (void)d_ws; (void)ws_size; (void)in_sizes; (void)n_in; (void)out_size;

    em_routing_kernel<<<dim3(8 * L_), dim3(512), 0, stream>>>(
        a_in, pose, W, beta_u, beta_a, out);
}